// Round 13
// baseline (223.491 us; speedup 1.0000x reference)
//
#include <hip/hip_runtime.h>
#include <stdint.h>

#define HDIM 64
#define TDIM 512
#define GB   16   // batches per block (one MFMA N-tile)

// ---- 4-wave MFMA RNN, ping-pong state, hand-scheduled step chain ----
// r12 (verified 721 cy/step, 154 us): ~360 cy/step is serial-chain stall
// (barrier -> 4x ds_read_b128 latency -> MFMA deps -> tanh -> pack -> drain
// -> barrier) at 1 wave/SIMD with nothing to overlap. r13 hand-schedules
// the chain (numerics bit-identical to r12):
//   1. ds_reads as inline asm + counted s_waitcnt lgkmcnt(2) +
//      sched_barrier(0) fence (m214-verified pattern): chunk-0 MFMAs run
//      while chunk-1 state reads are in flight.
//   2. Quad relayout {hi-c0, lo-c0, hi-c1, lo-c1} so the two state writes
//      merge into ONE ds_write2_b64 (offset1:128 = 1024 B).
//   3. Raw s_barrier with explicit single lgkmcnt(0) drain.
// Mapping/protocol unchanged (verified r9-r12):
//   transposed update S_new[64h x 16b] = tanh(xw + W'*S), state=B-operand,
//   phi(16w+4g+r) = 32*(w>>1)+8g+4*(w&1)+r on W_hh rows/W_ih/bias/fc_w,
//   f16 hi/lo 3-term product (f32 acc), K=2*log2(e) folded into W/bias,
//   bit-mask hi split + cvt_pkrtz pack, ping-pong, one barrier/step.
// Geometry (r11 lesson): B=4096 = 16 batches/CU exactly; 256 blocks x 4
// waves at 1 wave/SIMD is the unique full-chip non-duplicating packing.
// Precision (r12 calibration): observed 2e-3 absmax from ~1e-6/step noise
// => ~1e3 amplification; f16-only state (1e-4/step) would fail. Keep hi/lo.

typedef float    f32x4 __attribute__((ext_vector_type(4)));
typedef _Float16 f16x8 __attribute__((ext_vector_type(8)));
typedef unsigned int u32;
typedef unsigned int u32x2 __attribute__((ext_vector_type(2)));
typedef unsigned int u32x4 __attribute__((ext_vector_type(4)));

__device__ __forceinline__ u32 pk2(float a, float b) {
    return __builtin_bit_cast(u32, __builtin_amdgcn_cvt_pkrtz(a, b));
}
__device__ __forceinline__ float hi_mask(float v) {
    // top-13-mantissa-bit truncation: exactly f16-representable for |v|<=1
    return __builtin_bit_cast(float, __builtin_bit_cast(u32, v) & 0xFFFFE000u);
}
__device__ __forceinline__ f16x8 asf16(u32x4 q) {
    return __builtin_bit_cast(f16x8, q);
}

__global__ __launch_bounds__(256, 1)
__attribute__((amdgpu_waves_per_eu(1)))
void rnn_pp_asm(const float* __restrict__ x,
                const float* __restrict__ W_ih,
                const float* __restrict__ W_hh,
                const float* __restrict__ b_ih,
                const float* __restrict__ b_hh,
                const float* __restrict__ fc_w,
                const float* __restrict__ fc_b,
                float* __restrict__ out,
                int B)
{
    // [pingpong][quad][lane][dword]; quads: 0=hi-c0 1=lo-c0 2=hi-c1 3=lo-c1
    __shared__ __align__(16) u32 st[2][4][64][4];   // 8 KB
    __shared__ float xs[66][GB];                    // x chunk [t][b] (+2 pad)
    __shared__ float red[4][GB];                    // final reduction

    const int tid  = threadIdx.x;               // block = 4 waves
    const int lane = tid & 63;
    const int w    = tid >> 6;                  // wave id = output tile
    const int b    = lane & 15;                 // batch col (B/D col)
    const int g    = lane >> 4;                 // k-group / D row-group
    const int m16  = lane & 15;
    const int gb0  = blockIdx.x * GB;
    const int wc   = w >> 1;                    // chunk this wave feeds
    const int wh   = w & 1;                     // dword-pair within chunk

    const float K = 2.885390081777927f;         // 2*log2(e), folded into W & bias

    // ---- A-frags (tile w): rows phi(16w + m16), f16 hi/lo, K-scaled ----
    f16x8 Ahi0, Ahi1, Alo0, Alo1;               // chunk 0 / chunk 1
    {
        const int wr = 32*wc + 8*(m16 >> 2) + 4*wh + (m16 & 3);
        const float* wrow = W_hh + wr * HDIM;
        const f32x4 va0 = *(const f32x4*)(wrow + 8*g);
        const f32x4 vb0 = *(const f32x4*)(wrow + 8*g + 4);
        const f32x4 va1 = *(const f32x4*)(wrow + 32 + 8*g);
        const f32x4 vb1 = *(const f32x4*)(wrow + 32 + 8*g + 4);
#pragma unroll
        for (int e = 0; e < 4; ++e) {
            float v; _Float16 h;
            v = K*va0[e]; h = (_Float16)v; Ahi0[e]   = h; Alo0[e]   = (_Float16)(v - (float)h);
            v = K*vb0[e]; h = (_Float16)v; Ahi0[e+4] = h; Alo0[e+4] = (_Float16)(v - (float)h);
            v = K*va1[e]; h = (_Float16)v; Ahi1[e]   = h; Alo1[e]   = (_Float16)(v - (float)h);
            v = K*vb1[e]; h = (_Float16)v; Ahi1[e+4] = h; Alo1[e+4] = (_Float16)(v - (float)h);
        }
    }

    // ---- C-init constants: D reg r -> h-index 32wc + 8g + 4wh + r ----
    float wihc[4], biasc[4];
#pragma unroll
    for (int r = 0; r < 4; ++r) {
        const int idx = 32*wc + 8*g + 4*wh + r;
        wihc[r]  = K * W_ih[idx];
        biasc[r] = K * (b_ih[idx] + b_hh[idx]);
    }

    // zero both ping-pong state buffers (8 KB): h(0)=0
    {
        const u32x4 z = {0u, 0u, 0u, 0u};
        ((u32x4*)st)[tid]       = z;
        ((u32x4*)st)[tid + 256] = z;
    }

    // ---- hoisted LDS byte addresses (generic->LDS low 32 bits) ----
    const u32 st0 = (u32)(uintptr_t)&st[0][0][0][0];
    const u32 rd0 = st0 + lane * 16;            // read base, buffer 0
    const u32 rd1 = rd0 + 4096;                 // read base, buffer 1
    const u32 wrb = st0 + (2*wc) * 1024 + lane * 16 + wh * 8;
    const u32 wr0 = wrb;                        // write into buffer 0
    const u32 wr1 = wrb + 4096;                 // write into buffer 1

    const int sm = tid >> 4;                    // x staging: batch row
    const int tq = tid & 15;                    // t-quad
    const f32x4 zero4 = {0.f, 0.f, 0.f, 0.f};

    float hv0 = 0.f, hv1 = 0.f, hv2 = 0.f, hv3 = 0.f;

    // One timestep. RDA = state buffer to read, WRA = buffer to write.
    // Chain: issue 4 reads -> lgkmcnt(2) fence -> chunk-0 MFMAs (chunk-1
    // reads in flight) -> lgkmcnt(0) fence -> chunk-1 MFMAs -> tanh ->
    // pack -> ds_write2_b64 -> drain -> s_barrier.
#define STEP(XT, XN, TNEXT, RDA, WRA)                                         \
    {                                                                         \
        u32x4 q0, q1, q2, q3;                                                 \
        asm volatile("ds_read_b128 %0, %1 offset:0"    : "=v"(q0) : "v"(RDA));\
        asm volatile("ds_read_b128 %0, %1 offset:1024" : "=v"(q1) : "v"(RDA));\
        asm volatile("ds_read_b128 %0, %1 offset:2048" : "=v"(q2) : "v"(RDA));\
        asm volatile("ds_read_b128 %0, %1 offset:3072" : "=v"(q3) : "v"(RDA));\
        XN = xs[(TNEXT)][b];                       /* off-chain prefetch */   \
        f32x4 c1;                                                             \
        c1.x = fmaf(XT, wihc[0], biasc[0]);                                   \
        c1.y = fmaf(XT, wihc[1], biasc[1]);                                   \
        c1.z = fmaf(XT, wihc[2], biasc[2]);                                   \
        c1.w = fmaf(XT, wihc[3], biasc[3]);                                   \
        asm volatile("s_waitcnt lgkmcnt(2)");      /* q0,q1 complete */       \
        __builtin_amdgcn_sched_barrier(0);                                    \
        f32x4 c2, c3;                                                         \
        c1 = __builtin_amdgcn_mfma_f32_16x16x32_f16(Ahi0, asf16(q0), c1, 0, 0, 0);    \
        c2 = __builtin_amdgcn_mfma_f32_16x16x32_f16(Ahi0, asf16(q1), zero4, 0, 0, 0); \
        c3 = __builtin_amdgcn_mfma_f32_16x16x32_f16(Alo0, asf16(q0), zero4, 0, 0, 0); \
        asm volatile("s_waitcnt lgkmcnt(0)");      /* q2,q3 complete */       \
        __builtin_amdgcn_sched_barrier(0);                                    \
        c1 = __builtin_amdgcn_mfma_f32_16x16x32_f16(Ahi1, asf16(q2), c1, 0, 0, 0);    \
        c2 = __builtin_amdgcn_mfma_f32_16x16x32_f16(Ahi1, asf16(q3), c2, 0, 0, 0);    \
        c3 = __builtin_amdgcn_mfma_f32_16x16x32_f16(Alo1, asf16(q2), c3, 0, 0, 0);    \
        const f32x4 zsum = c1 + (c2 + c3);                                    \
        /* tanh(z) = 1 - 2/(1 + e^{2z}); inputs already K-scaled */           \
        hv0 = fmaf(-2.0f, __builtin_amdgcn_rcpf(__builtin_amdgcn_exp2f(zsum.x) + 1.0f), 1.0f); \
        hv1 = fmaf(-2.0f, __builtin_amdgcn_rcpf(__builtin_amdgcn_exp2f(zsum.y) + 1.0f), 1.0f); \
        hv2 = fmaf(-2.0f, __builtin_amdgcn_rcpf(__builtin_amdgcn_exp2f(zsum.z) + 1.0f), 1.0f); \
        hv3 = fmaf(-2.0f, __builtin_amdgcn_rcpf(__builtin_amdgcn_exp2f(zsum.w) + 1.0f), 1.0f); \
        const float h0 = hi_mask(hv0), h1 = hi_mask(hv1);                     \
        const float h2 = hi_mask(hv2), h3 = hi_mask(hv3);                     \
        u32x2 nh, nl;                                                         \
        nh.x = pk2(h0, h1);           nh.y = pk2(h2, h3);                     \
        nl.x = pk2(hv0-h0, hv1-h1);   nl.y = pk2(hv2-h2, hv3-h3);             \
        /* hi -> quad 2wc (offset0), lo -> quad 2wc+1 (offset1 = +1024 B) */  \
        asm volatile("ds_write2_b64 %0, %1, %2 offset0:0 offset1:128"         \
                     :: "v"(WRA), "v"(nh), "v"(nl));                          \
        asm volatile("s_waitcnt lgkmcnt(0)");      /* writes visible */       \
        __builtin_amdgcn_sched_barrier(0);                                    \
        __builtin_amdgcn_s_barrier();                                         \
        __builtin_amdgcn_sched_barrier(0);                                    \
    }

#pragma unroll 1
    for (int tc = 0; tc < TDIM/64; ++tc) {
        const f32x4 xv4 = *(const f32x4*)(x + (size_t)(gb0 + sm) * TDIM
                                            + tc*64 + tq*4);
        xs[tq*4 + 0][sm] = xv4.x;
        xs[tq*4 + 1][sm] = xv4.y;
        xs[tq*4 + 2][sm] = xv4.z;
        xs[tq*4 + 3][sm] = xv4.w;
        __syncthreads();    // publish xs (and the zeroed st at tc==0)

        float xt = xs[0][b], xn;
#pragma unroll 1
        for (int tj = 0; tj < 64; tj += 2) {
            // parity: step tj even reads buf0 writes buf1; odd the reverse
            STEP(xt, xn, tj + 1, rd0, wr1)
            STEP(xn, xt, tj + 2, rd1, wr0)
            // (tj=62 prefetches xs[64] -> pad row, discarded next chunk)
        }
    }
#undef STEP

    // ---- out[b] = sum_j h[j]*fc_w[j] + fc_b ----
    // Lane's 4 final h-values (exact f32): indices 32wc + 8g + 4wh + r.
    float acc = 0.0f;
    acc = fmaf(hv0, fc_w[32*wc + 8*g + 4*wh + 0], acc);
    acc = fmaf(hv1, fc_w[32*wc + 8*g + 4*wh + 1], acc);
    acc = fmaf(hv2, fc_w[32*wc + 8*g + 4*wh + 2], acc);
    acc = fmaf(hv3, fc_w[32*wc + 8*g + 4*wh + 3], acc);
    acc += __shfl_xor(acc, 16, 64);   // sum the 4 g-groups of this batch col
    acc += __shfl_xor(acc, 32, 64);
    if (lane < 16) red[w][lane] = acc;
    __syncthreads();
    if (tid < GB)
        out[gb0 + tid] = red[0][tid] + red[1][tid] + red[2][tid] + red[3][tid]
                       + fc_b[0];
}

extern "C" void kernel_launch(void* const* d_in, const int* in_sizes, int n_in,
                              void* d_out, int out_size, void* d_ws, size_t ws_size,
                              hipStream_t stream)
{
    const float* x    = (const float*)d_in[0];
    const float* W_ih = (const float*)d_in[1];
    const float* W_hh = (const float*)d_in[2];
    const float* b_ih = (const float*)d_in[3];
    const float* b_hh = (const float*)d_in[4];
    const float* fc_w = (const float*)d_in[5];
    const float* fc_b = (const float*)d_in[6];
    float* out = (float*)d_out;

    const int B = in_sizes[0] / TDIM;      // x is (B, T, 1)
    const int blocks = B / GB;             // 256 blocks x 4 waves = full chip

    rnn_pp_asm<<<blocks, 256, 0, stream>>>(
        x, W_ih, W_hh, b_ih, b_hh, fc_w, fc_b, out, B);
}

// Round 14
// 207.486 us; speedup vs baseline: 1.0771x; 1.0771x over previous
//
#include <hip/hip_runtime.h>
#include <stdint.h>

#define HDIM 64
#define TDIM 512
#define GB   16   // batches per block (one MFMA N-tile)

// ---- 4-wave MFMA RNN, ping-pong state, 1 barrier/step (r12 + micro-cuts) ----
// r13 lesson (808 cy/step, regressed from r12's 721): sched_barrier(0)
// pinning + asm ds_reads defeat the compiler's scheduler (guide m141) --
// the counted-wait overlap gained less than the pinning lost. r14 reverts
// to r12's fully compiler-scheduled loop and keeps only the two cuts that
// need no scheduling control:
//   1. Quad relayout {hi-c0, lo-c0, hi-c1, lo-c1}: each wave's two state
//      writes are 1024 B apart from one base -> compiler merges them into
//      one ds_write2_b64 (relayout correctness verified in r13).
//   2. Walking x-pointer (offsets become ds immediates) instead of per-step
//      xs[tj+1][b] index arithmetic.
// Protocol/mapping/numerics bit-identical to r12 (verified 154 us,
// absmax 0.001953125):
//   transposed update S_new[64h x 16b] = tanh(xw + W'*S), state=B-operand,
//   phi(16w+4g+r) = 32*(w>>1)+8g+4*(w&1)+r on W_hh rows/W_ih/bias/fc_w,
//   f16 hi/lo 3-term product (f32 acc), K=2*log2(e) folded into W/bias,
//   bit-mask hi split + cvt_pkrtz pack, ping-pong, compile-time parity,
//   ONE __syncthreads per step.
// Ladder (measured): r9 964 -> r10 830 (-barrier) -> r12 721 (-addr/movs)
// -> r13 808 (hand-sched, reverted). Decomposition space measured out:
// 1-wave 1275, 8-wave/half-chip net loss, K-split worse. Remaining 721 =
// ~255 VALU issue + ~96 MFMA + ~370 chain/barrier at the unique full-chip
// packing (B=4096 = 16 batches/CU exactly).

typedef float    f32x4 __attribute__((ext_vector_type(4)));
typedef _Float16 f16x8 __attribute__((ext_vector_type(8)));
typedef unsigned int u32;
typedef unsigned int u32x2 __attribute__((ext_vector_type(2)));
typedef unsigned int u32x4 __attribute__((ext_vector_type(4)));

__device__ __forceinline__ u32 pk2(float a, float b) {
    return __builtin_bit_cast(u32, __builtin_amdgcn_cvt_pkrtz(a, b));
}
__device__ __forceinline__ float hi_mask(float v) {
    // top-13-mantissa-bit truncation: exactly f16-representable for |v|<=1
    return __builtin_bit_cast(float, __builtin_bit_cast(u32, v) & 0xFFFFE000u);
}

__global__ __launch_bounds__(256, 1)
__attribute__((amdgpu_waves_per_eu(1)))
void rnn_pp_slim2(const float* __restrict__ x,
                  const float* __restrict__ W_ih,
                  const float* __restrict__ W_hh,
                  const float* __restrict__ b_ih,
                  const float* __restrict__ b_hh,
                  const float* __restrict__ fc_w,
                  const float* __restrict__ fc_b,
                  float* __restrict__ out,
                  int B)
{
    // [pingpong][quad][lane][dword]; quads: 0=hi-c0 1=lo-c0 2=hi-c1 3=lo-c1
    __shared__ __align__(16) u32 st[2][4][64][4];   // 8 KB
    __shared__ float xs[66][GB];                    // x chunk [t][b] (+2 pad)
    __shared__ float red[4][GB];                    // final reduction

    const int tid  = threadIdx.x;               // block = 4 waves
    const int lane = tid & 63;
    const int w    = tid >> 6;                  // wave id = output tile
    const int b    = lane & 15;                 // batch col (B/D col)
    const int g    = lane >> 4;                 // k-group / D row-group
    const int m16  = lane & 15;
    const int gb0  = blockIdx.x * GB;
    const int wc   = w >> 1;                    // chunk this wave feeds
    const int wh   = w & 1;                     // dword-pair within chunk

    const float K = 2.885390081777927f;         // 2*log2(e), folded into W & bias

    // ---- A-frags (tile w): rows phi(16w + m16), f16 hi/lo, K-scaled ----
    f16x8 Ahi0, Ahi1, Alo0, Alo1;               // chunk 0 / chunk 1
    {
        const int wr = 32*wc + 8*(m16 >> 2) + 4*wh + (m16 & 3);
        const float* wrow = W_hh + wr * HDIM;
        const f32x4 va0 = *(const f32x4*)(wrow + 8*g);
        const f32x4 vb0 = *(const f32x4*)(wrow + 8*g + 4);
        const f32x4 va1 = *(const f32x4*)(wrow + 32 + 8*g);
        const f32x4 vb1 = *(const f32x4*)(wrow + 32 + 8*g + 4);
#pragma unroll
        for (int e = 0; e < 4; ++e) {
            float v; _Float16 h;
            v = K*va0[e]; h = (_Float16)v; Ahi0[e]   = h; Alo0[e]   = (_Float16)(v - (float)h);
            v = K*vb0[e]; h = (_Float16)v; Ahi0[e+4] = h; Alo0[e+4] = (_Float16)(v - (float)h);
            v = K*va1[e]; h = (_Float16)v; Ahi1[e]   = h; Alo1[e]   = (_Float16)(v - (float)h);
            v = K*vb1[e]; h = (_Float16)v; Ahi1[e+4] = h; Alo1[e+4] = (_Float16)(v - (float)h);
        }
    }

    // ---- C-init constants: D reg r -> h-index 32wc + 8g + 4wh + r ----
    float wihc[4], biasc[4];
#pragma unroll
    for (int r = 0; r < 4; ++r) {
        const int idx = 32*wc + 8*g + 4*wh + r;
        wihc[r]  = K * W_ih[idx];
        biasc[r] = K * (b_ih[idx] + b_hh[idx]);
    }

    // zero both ping-pong state buffers (8 KB): h(0)=0
    {
        const u32x4 z = {0u, 0u, 0u, 0u};
        ((u32x4*)st)[tid]       = z;
        ((u32x4*)st)[tid + 256] = z;
    }

    const int sm = tid >> 4;                    // x staging: batch row
    const int tq = tid & 15;                    // t-quad
    const f32x4 zero4 = {0.f, 0.f, 0.f, 0.f};

    float hv0 = 0.f, hv1 = 0.f, hv2 = 0.f, hv3 = 0.f;

    // One timestep, compile-time parity PP. XT = this step's x (register);
    // XN = next step's x, loaded early off-chain via walking pointer xp
    // (row stride = GB floats -> ds immediate offsets).
    // Reads: quad q at +q*1024 from lane base. Writes: hi -> quad 2wc,
    // lo -> quad 2wc+1 (adjacent, 1024 B apart -> one ds_write2_b64).
#define STEP(PP, XT, XN, NOFF)                                                \
    {                                                                         \
        const f16x8 ih0 = __builtin_bit_cast(f16x8, *(const u32x4*)&st[PP][0][lane][0]); \
        const f16x8 il0 = __builtin_bit_cast(f16x8, *(const u32x4*)&st[PP][1][lane][0]); \
        const f16x8 ih1 = __builtin_bit_cast(f16x8, *(const u32x4*)&st[PP][2][lane][0]); \
        const f16x8 il1 = __builtin_bit_cast(f16x8, *(const u32x4*)&st[PP][3][lane][0]); \
        XN = xp[NOFF];                             /* off-chain prefetch */   \
        f32x4 c1, c2, c3;                                                     \
        c1.x = fmaf(XT, wihc[0], biasc[0]);                                   \
        c1.y = fmaf(XT, wihc[1], biasc[1]);                                   \
        c1.z = fmaf(XT, wihc[2], biasc[2]);                                   \
        c1.w = fmaf(XT, wihc[3], biasc[3]);                                   \
        c2 = zero4; c3 = zero4;                                               \
        /* 3 chains x 2-deep: hi*hi | hi*lo | lo*hi, chunks 0+1 */            \
        c1 = __builtin_amdgcn_mfma_f32_16x16x32_f16(Ahi0, ih0, c1, 0, 0, 0);  \
        c2 = __builtin_amdgcn_mfma_f32_16x16x32_f16(Ahi0, il0, c2, 0, 0, 0);  \
        c3 = __builtin_amdgcn_mfma_f32_16x16x32_f16(Alo0, ih0, c3, 0, 0, 0);  \
        c1 = __builtin_amdgcn_mfma_f32_16x16x32_f16(Ahi1, ih1, c1, 0, 0, 0);  \
        c2 = __builtin_amdgcn_mfma_f32_16x16x32_f16(Ahi1, il1, c2, 0, 0, 0);  \
        c3 = __builtin_amdgcn_mfma_f32_16x16x32_f16(Alo1, ih1, c3, 0, 0, 0);  \
        const f32x4 zsum = c1 + (c2 + c3);                                    \
        /* tanh(z) = 1 - 2/(1 + e^{2z}); inputs already K-scaled */           \
        hv0 = fmaf(-2.0f, __builtin_amdgcn_rcpf(__builtin_amdgcn_exp2f(zsum.x) + 1.0f), 1.0f); \
        hv1 = fmaf(-2.0f, __builtin_amdgcn_rcpf(__builtin_amdgcn_exp2f(zsum.y) + 1.0f), 1.0f); \
        hv2 = fmaf(-2.0f, __builtin_amdgcn_rcpf(__builtin_amdgcn_exp2f(zsum.z) + 1.0f), 1.0f); \
        hv3 = fmaf(-2.0f, __builtin_amdgcn_rcpf(__builtin_amdgcn_exp2f(zsum.w) + 1.0f), 1.0f); \
        const float h0 = hi_mask(hv0), h1 = hi_mask(hv1);                     \
        const float h2 = hi_mask(hv2), h3 = hi_mask(hv3);                     \
        u32x2 nh, nl;                                                         \
        nh.x = pk2(h0, h1);           nh.y = pk2(h2, h3);                     \
        nl.x = pk2(hv0-h0, hv1-h1);   nl.y = pk2(hv2-h2, hv3-h3);             \
        /* write h(t+1): hi and lo quads adjacent (1024 B) -> ds_write2_b64.*/\
        /* WAR-safe: reads of st[PP^1] were in step t-1, before its barrier.*/\
        *(u32x2*)&st[(PP) ^ 1][2*wc    ][lane][2*wh] = nh;                    \
        *(u32x2*)&st[(PP) ^ 1][2*wc + 1][lane][2*wh] = nl;                    \
        __syncthreads();                                                      \
    }

#pragma unroll 1
    for (int tc = 0; tc < TDIM/64; ++tc) {
        const f32x4 xv4 = *(const f32x4*)(x + (size_t)(gb0 + sm) * TDIM
                                            + tc*64 + tq*4);
        xs[tq*4 + 0][sm] = xv4.x;
        xs[tq*4 + 1][sm] = xv4.y;
        xs[tq*4 + 2][sm] = xv4.z;
        xs[tq*4 + 3][sm] = xv4.w;
        __syncthreads();    // publish xs (and the zeroed st at tc==0)

        const float* xp = &xs[0][b];
        float xt = xp[0], xn;
#pragma unroll 1
        for (int tj = 0; tj < 64; tj += 2) {
            // global parity: tc*64 is even, so step tj has parity tj&1
            STEP(0, xt, xn, GB)         // reads st[0], writes st[1]
            STEP(1, xn, xt, 2*GB)       // reads st[1], writes st[0]
            xp += 2*GB;
            // (tj=62 prefetches row 64 -> pad row, discarded next chunk)
        }
    }
#undef STEP

    // ---- out[b] = sum_j h[j]*fc_w[j] + fc_b ----
    // Lane's 4 final h-values (exact f32): indices 32wc + 8g + 4wh + r.
    float acc = 0.0f;
    acc = fmaf(hv0, fc_w[32*wc + 8*g + 4*wh + 0], acc);
    acc = fmaf(hv1, fc_w[32*wc + 8*g + 4*wh + 1], acc);
    acc = fmaf(hv2, fc_w[32*wc + 8*g + 4*wh + 2], acc);
    acc = fmaf(hv3, fc_w[32*wc + 8*g + 4*wh + 3], acc);
    acc += __shfl_xor(acc, 16, 64);   // sum the 4 g-groups of this batch col
    acc += __shfl_xor(acc, 32, 64);
    if (lane < 16) red[w][lane] = acc;
    __syncthreads();
    if (tid < GB)
        out[gb0 + tid] = red[0][tid] + red[1][tid] + red[2][tid] + red[3][tid]
                       + fc_b[0];
}

extern "C" void kernel_launch(void* const* d_in, const int* in_sizes, int n_in,
                              void* d_out, int out_size, void* d_ws, size_t ws_size,
                              hipStream_t stream)
{
    const float* x    = (const float*)d_in[0];
    const float* W_ih = (const float*)d_in[1];
    const float* W_hh = (const float*)d_in[2];
    const float* b_ih = (const float*)d_in[3];
    const float* b_hh = (const float*)d_in[4];
    const float* fc_w = (const float*)d_in[5];
    const float* fc_b = (const float*)d_in[6];
    float* out = (float*)d_out;

    const int B = in_sizes[0] / TDIM;      // x is (B, T, 1)
    const int blocks = B / GB;             // 256 blocks x 4 waves = full chip

    rnn_pp_slim2<<<blocks, 256, 0, stream>>>(
        x, W_ih, W_hh, b_ih, b_hh, fc_w, fc_b, out, B);
}